// Round 2
// baseline (422.661 us; speedup 1.0000x reference)
//
#include <hip/hip_runtime.h>

// MultiHeadedAttention with relative position (B=2, T=1024, D=1024, H=16, DK=64)
// Pipeline: proj(q,k), projT(v->vT) -> S=Bp+bias+mask -> S=softmax(qk^T+S) in-place ->
//           X0=attn@pos_v (bf16) -> X=X0+attn@v (vT, no LDS) -> out=X@Wo+bo
// All matmuls bf16 MFMA 16x16x32 with fp32 accum; abs threshold 6.4e-3 permits.

#define DEV __device__ __forceinline__

typedef short bf16x8 __attribute__((ext_vector_type(8)));
typedef float f32x4 __attribute__((ext_vector_type(4)));

DEV short f2b(float f) {
  unsigned u = __builtin_bit_cast(unsigned, f);
  u = (u + 0x7FFFu + ((u >> 16) & 1u)) >> 16;
  return (short)u;
}
DEV float b2f(short s) {
  unsigned u = ((unsigned)(unsigned short)s) << 16;
  return __builtin_bit_cast(float, u);
}

#define MFMA(a, b, c) __builtin_amdgcn_mfma_f32_16x16x32_bf16(a, b, c, 0, 0, 0)

// ---------------------------------------------------------------------------
// K1: projection GEMM: out[(b,h,t,dk)] = bf16( (in[(b,t),:] @ W + bias) * scale )
// M=2048 (b*T+t), N=1024 (h*64+dk), K=1024. BM=BN=64, BK=32, 4 waves.
__global__ __launch_bounds__(256) void k_proj(
    const float* __restrict__ in, const float* __restrict__ W,
    const float* __restrict__ bias, short* __restrict__ out, float scale) {
  __shared__ short As[64][40];  // [m][k], +8 pad
  __shared__ short Bs[64][40];  // [n][k] (transposed), +8 pad
  const int n0 = blockIdx.x * 64;
  const int m0 = blockIdx.y * 64;
  const int tid = threadIdx.x;
  const int w = tid >> 6, l = tid & 63, lg = l >> 4, lr = l & 15;
  const int wm = (w >> 1) * 2, wn = (w & 1) * 2;  // 16-tile units
  f32x4 acc[2][2] = {};
  for (int k0 = 0; k0 < 1024; k0 += 32) {
#pragma unroll
    for (int rr = 0; rr < 2; ++rr) {  // stage A 64x32 fp32 -> bf16
      int r = (tid >> 3) + rr * 32, c4 = (tid & 7) * 4;
      const float4 vA = *(const float4*)(in + (size_t)(m0 + r) * 1024 + k0 + c4);
      As[r][c4 + 0] = f2b(vA.x); As[r][c4 + 1] = f2b(vA.y);
      As[r][c4 + 2] = f2b(vA.z); As[r][c4 + 3] = f2b(vA.w);
    }
#pragma unroll
    for (int rr = 0; rr < 2; ++rr) {  // stage B 32x64 fp32 -> bf16 transposed
      int kk = (tid >> 4) + rr * 16, n4 = (tid & 15) * 4;
      const float4 vB = *(const float4*)(W + (size_t)(k0 + kk) * 1024 + n0 + n4);
      Bs[n4 + 0][kk] = f2b(vB.x); Bs[n4 + 1][kk] = f2b(vB.y);
      Bs[n4 + 2][kk] = f2b(vB.z); Bs[n4 + 3][kk] = f2b(vB.w);
    }
    __syncthreads();
    bf16x8 af[2], bfr[2];
#pragma unroll
    for (int mi = 0; mi < 2; ++mi) af[mi] = *(const bf16x8*)&As[(wm + mi) * 16 + lr][lg * 8];
#pragma unroll
    for (int ni = 0; ni < 2; ++ni) bfr[ni] = *(const bf16x8*)&Bs[(wn + ni) * 16 + lr][lg * 8];
#pragma unroll
    for (int mi = 0; mi < 2; ++mi)
#pragma unroll
      for (int ni = 0; ni < 2; ++ni) acc[mi][ni] = MFMA(af[mi], bfr[ni], acc[mi][ni]);
    __syncthreads();
  }
#pragma unroll
  for (int mi = 0; mi < 2; ++mi)
#pragma unroll
    for (int ni = 0; ni < 2; ++ni)
#pragma unroll
      for (int r = 0; r < 4; ++r) {
        int m = m0 + (wm + mi) * 16 + lg * 4 + r;
        int n = n0 + (wn + ni) * 16 + lr;
        float val = (acc[mi][ni][r] + bias[n]) * scale;
        int b = m >> 10, t = m & 1023, h = n >> 6, dk = n & 63;
        out[((size_t)(b * 16 + h) * 1024 + t) * 64 + dk] = f2b(val);
      }
}

// ---------------------------------------------------------------------------
// K1T: same GEMM but stores transposed per head: vT[bh][dk][t].
// Block covers 64 t (one b) x 64 n (one h): 64 rows x 128B of vT -> L2 assembles lines.
__global__ __launch_bounds__(256) void k_projT(
    const float* __restrict__ in, const float* __restrict__ W,
    const float* __restrict__ bias, short* __restrict__ out) {
  __shared__ short As[64][40];
  __shared__ short Bs[64][40];
  const int n0 = blockIdx.x * 64;
  const int m0 = blockIdx.y * 64;
  const int tid = threadIdx.x;
  const int w = tid >> 6, l = tid & 63, lg = l >> 4, lr = l & 15;
  const int wm = (w >> 1) * 2, wn = (w & 1) * 2;
  f32x4 acc[2][2] = {};
  for (int k0 = 0; k0 < 1024; k0 += 32) {
#pragma unroll
    for (int rr = 0; rr < 2; ++rr) {
      int r = (tid >> 3) + rr * 32, c4 = (tid & 7) * 4;
      const float4 vA = *(const float4*)(in + (size_t)(m0 + r) * 1024 + k0 + c4);
      As[r][c4 + 0] = f2b(vA.x); As[r][c4 + 1] = f2b(vA.y);
      As[r][c4 + 2] = f2b(vA.z); As[r][c4 + 3] = f2b(vA.w);
    }
#pragma unroll
    for (int rr = 0; rr < 2; ++rr) {
      int kk = (tid >> 4) + rr * 16, n4 = (tid & 15) * 4;
      const float4 vB = *(const float4*)(W + (size_t)(k0 + kk) * 1024 + n0 + n4);
      Bs[n4 + 0][kk] = f2b(vB.x); Bs[n4 + 1][kk] = f2b(vB.y);
      Bs[n4 + 2][kk] = f2b(vB.z); Bs[n4 + 3][kk] = f2b(vB.w);
    }
    __syncthreads();
    bf16x8 af[2], bfr[2];
#pragma unroll
    for (int mi = 0; mi < 2; ++mi) af[mi] = *(const bf16x8*)&As[(wm + mi) * 16 + lr][lg * 8];
#pragma unroll
    for (int ni = 0; ni < 2; ++ni) bfr[ni] = *(const bf16x8*)&Bs[(wn + ni) * 16 + lr][lg * 8];
#pragma unroll
    for (int mi = 0; mi < 2; ++mi)
#pragma unroll
      for (int ni = 0; ni < 2; ++ni) acc[mi][ni] = MFMA(af[mi], bfr[ni], acc[mi][ni]);
    __syncthreads();
  }
#pragma unroll
  for (int mi = 0; mi < 2; ++mi)
#pragma unroll
    for (int ni = 0; ni < 2; ++ni)
#pragma unroll
      for (int r = 0; r < 4; ++r) {
        int m = m0 + (wm + mi) * 16 + lg * 4 + r;
        int n = n0 + (wn + ni) * 16 + lr;
        float val = acc[mi][ni][r] + bias[n];
        int b = m >> 10, t = m & 1023, h = n >> 6, dk = n & 63;
        out[(((size_t)(b * 16 + h) * 64 + dk) << 10) + t] = f2b(val);
      }
}

// ---------------------------------------------------------------------------
// K2a: S[bh,t,s] = q[bh,t,:]·pos_k[t,s,:] + bias[h,t,s]  (or -1e30 if masked)
// grid (s/256, t); block 256 = 4 waves, each wave 64 cols; M=32 (bh).
__global__ __launch_bounds__(256) void k_posk_bias(
    const short* __restrict__ q, const float* __restrict__ pos_k,
    const float* __restrict__ rab, const int* __restrict__ mask,
    short* __restrict__ S) {
  const int t = blockIdx.y;
  const int tid = threadIdx.x;
  const int w = tid >> 6, l = tid & 63, lg = l >> 4, lr = l & 15;
  const int s0 = blockIdx.x * 256 + w * 64;
  bf16x8 af[2][2];
#pragma unroll
  for (int mi = 0; mi < 2; ++mi)
#pragma unroll
    for (int kk = 0; kk < 2; ++kk) {
      int bh = mi * 16 + lr;
      af[mi][kk] = *(const bf16x8*)(q + ((size_t)bh * 1024 + t) * 64 + kk * 32 + lg * 8);
    }
  f32x4 acc[2][4] = {};
#pragma unroll
  for (int ni = 0; ni < 4; ++ni) {
    int s = s0 + ni * 16 + lr;
#pragma unroll
    for (int kk = 0; kk < 2; ++kk) {
      const float* pk = pos_k + ((size_t)t * 1024 + s) * 64 + kk * 32 + lg * 8;
      const float4 p0 = *(const float4*)pk;
      const float4 p1 = *(const float4*)(pk + 4);
      bf16x8 bfr;
      bfr[0] = f2b(p0.x); bfr[1] = f2b(p0.y); bfr[2] = f2b(p0.z); bfr[3] = f2b(p0.w);
      bfr[4] = f2b(p1.x); bfr[5] = f2b(p1.y); bfr[6] = f2b(p1.z); bfr[7] = f2b(p1.w);
#pragma unroll
      for (int mi = 0; mi < 2; ++mi) acc[mi][ni] = MFMA(af[mi][kk], bfr, acc[mi][ni]);
    }
  }
#pragma unroll
  for (int ni = 0; ni < 4; ++ni) {
    int s = s0 + ni * 16 + lr;
    int msk0 = mask[(size_t)t * 1024 + s];
    int msk1 = mask[(size_t)(1024 + t) * 1024 + s];
#pragma unroll
    for (int r = 0; r < 4; ++r) {
      int h = lg * 4 + r;  // same h for both b (rows mi*16+h)
      float bv = rab[((size_t)h * 1024 + t) * 1024 + s];
      float v0 = acc[0][ni][r] + bv;
      float v1 = acc[1][ni][r] + bv;
      if (msk0 == 0) v0 = -1e30f;
      if (msk1 == 0) v1 = -1e30f;
      S[((size_t)h * 1024 + t) * 1024 + s] = f2b(v0);
      S[((size_t)(16 + h) * 1024 + t) * 1024 + s] = f2b(v1);
    }
  }
}

// ---------------------------------------------------------------------------
// K2b: S = softmax_rows( q@k^T + S ), in place. grid (T/32, bh); 8 waves.
__global__ __launch_bounds__(512) void k_attn_softmax(
    const short* __restrict__ q, const short* __restrict__ kmat,
    short* __restrict__ S) {
  const int bh = blockIdx.y;
  const int tid = threadIdx.x;
  const int w = tid >> 6, l = tid & 63, lg = l >> 4, lr = l & 15;
  const int wm = w >> 2, wn = w & 3;
  const int t0 = blockIdx.x * 32 + wm * 16;
  const int scol = wn * 256;
  __shared__ float redA[32][4];
  __shared__ float redB[32][4];

  bf16x8 af[2];
#pragma unroll
  for (int kk = 0; kk < 2; ++kk)
    af[kk] = *(const bf16x8*)(q + ((size_t)bh * 1024 + (t0 + lr)) * 64 + kk * 32 + lg * 8);

  f32x4 acc[16];
#pragma unroll
  for (int ni = 0; ni < 16; ++ni) {
    int s = scol + ni * 16 + lr;
    const short* kp = kmat + ((size_t)bh * 1024 + s) * 64 + lg * 8;
    bf16x8 b0 = *(const bf16x8*)kp;
    bf16x8 b1 = *(const bf16x8*)(kp + 32);
    f32x4 a = {};
    a = MFMA(af[0], b0, a);
    a = MFMA(af[1], b1, a);
    acc[ni] = a;
  }
#pragma unroll
  for (int ni = 0; ni < 16; ++ni)
#pragma unroll
    for (int r = 0; r < 4; ++r) {
      int tt = t0 + lg * 4 + r;
      int s = scol + ni * 16 + lr;
      acc[ni][r] += b2f(S[((size_t)bh * 1024 + tt) * 1024 + s]);
    }
  float pm[4];
#pragma unroll
  for (int r = 0; r < 4; ++r) {
    float m = acc[0][r];
#pragma unroll
    for (int ni = 1; ni < 16; ++ni) m = fmaxf(m, acc[ni][r]);
    m = fmaxf(m, __shfl_xor(m, 1));
    m = fmaxf(m, __shfl_xor(m, 2));
    m = fmaxf(m, __shfl_xor(m, 4));
    m = fmaxf(m, __shfl_xor(m, 8));
    pm[r] = m;
  }
  if (lr == 0) {
#pragma unroll
    for (int r = 0; r < 4; ++r) redA[wm * 16 + lg * 4 + r][wn] = pm[r];
  }
  __syncthreads();
  float rowm[4];
#pragma unroll
  for (int r = 0; r < 4; ++r) {
    int row = wm * 16 + lg * 4 + r;
    rowm[r] = fmaxf(fmaxf(redA[row][0], redA[row][1]), fmaxf(redA[row][2], redA[row][3]));
  }
  float rs[4];
#pragma unroll
  for (int r = 0; r < 4; ++r) {
    float sum = 0.f;
#pragma unroll
    for (int ni = 0; ni < 16; ++ni) {
      float e = __expf(acc[ni][r] - rowm[r]);
      acc[ni][r] = e;
      sum += e;
    }
    sum += __shfl_xor(sum, 1);
    sum += __shfl_xor(sum, 2);
    sum += __shfl_xor(sum, 4);
    sum += __shfl_xor(sum, 8);
    rs[r] = sum;
  }
  if (lr == 0) {
#pragma unroll
    for (int r = 0; r < 4; ++r) redB[wm * 16 + lg * 4 + r][wn] = rs[r];
  }
  __syncthreads();
#pragma unroll
  for (int r = 0; r < 4; ++r) {
    int row = wm * 16 + lg * 4 + r;
    float inv = 1.0f / (redB[row][0] + redB[row][1] + redB[row][2] + redB[row][3]);
    int tt = t0 + lg * 4 + r;
#pragma unroll
    for (int ni = 0; ni < 16; ++ni) {
      int s = scol + ni * 16 + lr;
      S[((size_t)bh * 1024 + tt) * 1024 + s] = f2b(acc[ni][r] * inv);
    }
  }
}

// ---------------------------------------------------------------------------
// K3: X0h[b,t,h*64+dk] = bf16( sum_s attn[bh,t,s] * pos_v[t,s,dk] ).  grid (T); 4 waves.
// pos_v staged row-major [s][dk] ld=66 (odd dword stride): float4 loads,
// 2-way (free) b32 writes; B-frags via 8x ds_read_u16, all-32-banks distinct.
__global__ __launch_bounds__(256) void k_posv(
    const short* __restrict__ S, const float* __restrict__ pos_v,
    short* __restrict__ X0h) {
  const int t = blockIdx.x;
  const int tid = threadIdx.x;
  const int w = tid >> 6, l = tid & 63, lg = l >> 4, lr = l & 15;
  const int mi = w >> 1;       // bh tile (0/1)
  const int nb = (w & 1) * 2;  // dk-tile base
  __shared__ short pv[256][66];  // [s][dk], ld 66 shorts = 33 dwords
  f32x4 acc[2] = {};
  const int srow = tid >> 4;        // staging: 16 s-rows/iter
  const int dk4 = (tid & 15) * 4;   // 4 dk per thread
  for (int c = 0; c < 4; ++c) {
    int sc = c * 256;
    if (c) __syncthreads();
#pragma unroll
    for (int it = 0; it < 16; ++it) {
      int s = srow + it * 16;
      float4 p = *(const float4*)(pos_v + ((size_t)t * 1024 + sc + s) * 64 + dk4);
      unsigned p0 = (unsigned)(unsigned short)f2b(p.x) | ((unsigned)(unsigned short)f2b(p.y) << 16);
      unsigned p1 = (unsigned)(unsigned short)f2b(p.z) | ((unsigned)(unsigned short)f2b(p.w) << 16);
      *(unsigned*)&pv[s][dk4] = p0;
      *(unsigned*)&pv[s][dk4 + 2] = p1;
    }
    __syncthreads();
    const int bh = mi * 16 + lr;
#pragma unroll
    for (int kk = 0; kk < 8; ++kk) {
      bf16x8 afr = *(const bf16x8*)(S + ((size_t)bh * 1024 + t) * 1024 + sc + kk * 32 + lg * 8);
#pragma unroll
      for (int ni = 0; ni < 2; ++ni) {
        int dk = (nb + ni) * 16 + lr;
        bf16x8 bfr;
#pragma unroll
        for (int j = 0; j < 8; ++j) bfr[j] = pv[kk * 32 + lg * 8 + j][dk];
        acc[ni] = MFMA(afr, bfr, acc[ni]);
      }
    }
  }
#pragma unroll
  for (int ni = 0; ni < 2; ++ni)
#pragma unroll
    for (int r = 0; r < 4; ++r) {
      int bh = mi * 16 + lg * 4 + r;
      int b = bh >> 4, h = bh & 15;
      int dk = (nb + ni) * 16 + lr;
      X0h[((size_t)(b * 1024 + t)) * 1024 + h * 64 + dk] = f2b(acc[ni][r]);
    }
}

// ---------------------------------------------------------------------------
// K4: X[b,t,h*64+dk] = bf16( X0h + sum_s attn[bh,t,s]*v[bh,s,dk] )
// grid (T/128, bh); 4 waves, NO LDS: B-frags contiguous from vT (L2-resident).
__global__ __launch_bounds__(256) void k_av(
    const short* __restrict__ S, const short* __restrict__ vT,
    const short* __restrict__ X0h, short* __restrict__ X) {
  const int bh = blockIdx.y;
  const int tt0 = blockIdx.x * 128;
  const int tid = threadIdx.x;
  const int w = tid >> 6, l = tid & 63, lg = l >> 4, lr = l & 15;
  const short* vbase = vT + ((size_t)bh << 16);
  const short* sbase = S + ((size_t)bh << 20);
  f32x4 acc[2][4] = {};
#pragma unroll 4
  for (int kk = 0; kk < 32; ++kk) {
    bf16x8 afr[2];
#pragma unroll
    for (int mi = 0; mi < 2; ++mi) {
      int tt = tt0 + (w * 2 + mi) * 16 + lr;
      afr[mi] = *(const bf16x8*)(sbase + ((size_t)tt << 10) + kk * 32 + lg * 8);
    }
#pragma unroll
    for (int ni = 0; ni < 4; ++ni) {
      bf16x8 bfr = *(const bf16x8*)(vbase + ((ni * 16 + lr) << 10) + kk * 32 + lg * 8);
#pragma unroll
      for (int mi = 0; mi < 2; ++mi) acc[mi][ni] = MFMA(afr[mi], bfr, acc[mi][ni]);
    }
  }
  const int b = bh >> 4, h = bh & 15;
#pragma unroll
  for (int mi = 0; mi < 2; ++mi)
#pragma unroll
    for (int ni = 0; ni < 4; ++ni)
#pragma unroll
      for (int r = 0; r < 4; ++r) {
        int tt = tt0 + (w * 2 + mi) * 16 + lg * 4 + r;
        int d = h * 64 + ni * 16 + lr;
        size_t idx = ((size_t)(b * 1024 + tt)) * 1024 + d;
        X[idx] = f2b(b2f(X0h[idx]) + acc[mi][ni][r]);
      }
}

// ---------------------------------------------------------------------------
// K5: out = X @ Wo + bo  (fp32 out).
__global__ __launch_bounds__(256) void k_oproj(
    const short* __restrict__ X, const float* __restrict__ W,
    const float* __restrict__ bias, float* __restrict__ out) {
  __shared__ short As[64][40];
  __shared__ short Bs[64][40];
  const int n0 = blockIdx.x * 64;
  const int m0 = blockIdx.y * 64;
  const int tid = threadIdx.x;
  const int w = tid >> 6, l = tid & 63, lg = l >> 4, lr = l & 15;
  const int wm = (w >> 1) * 2, wn = (w & 1) * 2;
  f32x4 acc[2][2] = {};
  for (int k0 = 0; k0 < 1024; k0 += 32) {
    {
      int r = tid >> 2, c8 = (tid & 3) * 8;
      bf16x8 vA = *(const bf16x8*)(X + (size_t)(m0 + r) * 1024 + k0 + c8);
      *(bf16x8*)&As[r][c8] = vA;
    }
#pragma unroll
    for (int rr = 0; rr < 2; ++rr) {
      int kk = (tid >> 4) + rr * 16, n4 = (tid & 15) * 4;
      const float4 vB = *(const float4*)(W + (size_t)(k0 + kk) * 1024 + n0 + n4);
      Bs[n4 + 0][kk] = f2b(vB.x); Bs[n4 + 1][kk] = f2b(vB.y);
      Bs[n4 + 2][kk] = f2b(vB.z); Bs[n4 + 3][kk] = f2b(vB.w);
    }
    __syncthreads();
    bf16x8 af[2], bfr[2];
#pragma unroll
    for (int mi = 0; mi < 2; ++mi) af[mi] = *(const bf16x8*)&As[(wm + mi) * 16 + lr][lg * 8];
#pragma unroll
    for (int ni = 0; ni < 2; ++ni) bfr[ni] = *(const bf16x8*)&Bs[(wn + ni) * 16 + lr][lg * 8];
#pragma unroll
    for (int mi = 0; mi < 2; ++mi)
#pragma unroll
      for (int ni = 0; ni < 2; ++ni) acc[mi][ni] = MFMA(af[mi], bfr[ni], acc[mi][ni]);
    __syncthreads();
  }
#pragma unroll
  for (int mi = 0; mi < 2; ++mi)
#pragma unroll
    for (int ni = 0; ni < 2; ++ni)
#pragma unroll
      for (int r = 0; r < 4; ++r) {
        int m = m0 + (wm + mi) * 16 + lg * 4 + r;
        int n = n0 + (wn + ni) * 16 + lr;
        out[(size_t)m * 1024 + n] = acc[mi][ni][r] + bias[n];
      }
}

// ---------------------------------------------------------------------------
extern "C" void kernel_launch(void* const* d_in, const int* in_sizes, int n_in,
                              void* d_out, int out_size, void* d_ws, size_t ws_size,
                              hipStream_t stream) {
  (void)in_sizes; (void)n_in; (void)out_size; (void)ws_size;
  const float* query = (const float*)d_in[0];
  const float* key   = (const float*)d_in[1];
  const float* value = (const float*)d_in[2];
  const float* pos_k = (const float*)d_in[3];
  const float* pos_v = (const float*)d_in[4];
  const int*   mask  = (const int*)d_in[5];
  const float* rab   = (const float*)d_in[6];
  const float* Wq = (const float*)d_in[7];
  const float* bq = (const float*)d_in[8];
  const float* Wk = (const float*)d_in[9];
  const float* bk = (const float*)d_in[10];
  const float* Wv = (const float*)d_in[11];
  const float* bv = (const float*)d_in[12];
  const float* Wo = (const float*)d_in[13];
  const float* bo = (const float*)d_in[14];
  float* out = (float*)d_out;

  const size_t M2 = 2ull * 1024 * 1024;  // B*H*T*DK elements
  short* q  = (short*)d_ws;
  short* k  = q + M2;
  short* vT = k + M2;                      // [bh][dk][t]
  short* S  = vT + M2;                     // 32M bf16 (B,H,T,T)
  short* X0h = S + 32ull * 1024 * 1024;    // bf16 (B,T,D)
  short* X   = X0h + M2;

  k_proj<<<dim3(16, 32), dim3(256), 0, stream>>>(query, Wq, bq, q, 0.125f);
  k_proj<<<dim3(16, 32), dim3(256), 0, stream>>>(key, Wk, bk, k, 1.0f);
  k_projT<<<dim3(16, 32), dim3(256), 0, stream>>>(value, Wv, bv, vT);
  k_posk_bias<<<dim3(4, 1024), dim3(256), 0, stream>>>(q, pos_k, rab, mask, S);
  k_attn_softmax<<<dim3(32, 32), dim3(512), 0, stream>>>(q, k, S);
  k_posv<<<dim3(1024), dim3(256), 0, stream>>>(S, pos_v, X0h);
  k_av<<<dim3(8, 32), dim3(256), 0, stream>>>(S, vT, X0h, X);
  k_oproj<<<dim3(16, 32), dim3(256), 0, stream>>>(X, Wo, bo, out);
}

// Round 3
// 319.276 us; speedup vs baseline: 1.3238x; 1.3238x over previous
//
#include <hip/hip_runtime.h>

// MultiHeadedAttention with relative position (B=2, T=1024, D=1024, H=16, DK=64)
// Pipeline: cvt(inputs->bf16), wtrans(W->bf16 [n][k]) -> proj(q,k), projT(v->vT)
//  -> S=Bp+bias+mask -> S=softmax(qk^T+S) in-place -> X0=attn@pos_v -> X=X0+attn@v
//  -> out=X@Wo+bo.  All matmuls bf16 MFMA 16x16x32, fp32 accum.

#define DEV __device__ __forceinline__

typedef short bf16x8 __attribute__((ext_vector_type(8)));
typedef float f32x4 __attribute__((ext_vector_type(4)));

DEV short f2b(float f) {
  unsigned u = __builtin_bit_cast(unsigned, f);
  u = (u + 0x7FFFu + ((u >> 16) & 1u)) >> 16;
  return (short)u;
}
DEV float b2f(short s) {
  unsigned u = ((unsigned)(unsigned short)s) << 16;
  return __builtin_bit_cast(float, u);
}

#define MFMA(a, b, c) __builtin_amdgcn_mfma_f32_16x16x32_bf16(a, b, c, 0, 0, 0)

// ---------------------------------------------------------------------------
// P1: fp32 -> bf16 flat convert for query/key/value (2M elems each).
__global__ __launch_bounds__(256) void k_cvt3(
    const float* __restrict__ a, const float* __restrict__ b, const float* __restrict__ c,
    short* __restrict__ oa, short* __restrict__ ob, short* __restrict__ oc) {
  const float* src = blockIdx.y == 0 ? a : (blockIdx.y == 1 ? b : c);
  short* dst = blockIdx.y == 0 ? oa : (blockIdx.y == 1 ? ob : oc);
  size_t i = ((size_t)blockIdx.x * 256 + threadIdx.x) * 8;
  float4 p0 = *(const float4*)(src + i);
  float4 p1 = *(const float4*)(src + i + 4);
  bf16x8 o;
  o[0] = f2b(p0.x); o[1] = f2b(p0.y); o[2] = f2b(p0.z); o[3] = f2b(p0.w);
  o[4] = f2b(p1.x); o[5] = f2b(p1.y); o[6] = f2b(p1.z); o[7] = f2b(p1.w);
  *(bf16x8*)(dst + i) = o;
}

// P2: W [k][n] fp32 -> WT [n][k] bf16, 64x64 tiles via LDS.
__global__ __launch_bounds__(256) void k_wtrans4(
    const float* __restrict__ w0, const float* __restrict__ w1,
    const float* __restrict__ w2, const float* __restrict__ w3,
    short* __restrict__ o0, short* __restrict__ o1,
    short* __restrict__ o2, short* __restrict__ o3) {
  const float* src; short* dst;
  switch (blockIdx.z) {
    case 0: src = w0; dst = o0; break;
    case 1: src = w1; dst = o1; break;
    case 2: src = w2; dst = o2; break;
    default: src = w3; dst = o3;
  }
  __shared__ short LW[64][74];
  const int tid = threadIdx.x;
  const int k0 = blockIdx.y * 64, n0 = blockIdx.x * 64;
  {
    int c4 = (tid & 15) * 4;
#pragma unroll
    for (int i = 0; i < 4; ++i) {
      int r = (tid >> 4) + i * 16;
      float4 v = *(const float4*)(src + (size_t)(k0 + r) * 1024 + n0 + c4);
      LW[r][c4 + 0] = f2b(v.x); LW[r][c4 + 1] = f2b(v.y);
      LW[r][c4 + 2] = f2b(v.z); LW[r][c4 + 3] = f2b(v.w);
    }
  }
  __syncthreads();
  {
    int n = tid >> 2, kb = (tid & 3) * 16;
#pragma unroll
    for (int j2 = 0; j2 < 2; ++j2) {
      int kk = kb + j2 * 8;
      bf16x8 o;
#pragma unroll
      for (int j = 0; j < 8; ++j) o[j] = LW[kk + j][n];
      *(bf16x8*)(dst + (size_t)(n0 + n) * 1024 + k0 + kk) = o;
    }
  }
}

// ---------------------------------------------------------------------------
// K1: projection GEMM, pure bf16: out[(b,h,t,dk)] = bf16((A@W + bias)*scale)
// A [2048][1024] bf16, WT [n][k] bf16. BM=BN=64, BK=32, 4 waves.
__global__ __launch_bounds__(256) void k_proj(
    const short* __restrict__ A, const short* __restrict__ WT,
    const float* __restrict__ bias, short* __restrict__ out, float scale) {
  __shared__ short As[64][40];
  __shared__ short Bs[64][40];
  const int n0 = blockIdx.x * 64, m0 = blockIdx.y * 64;
  const int tid = threadIdx.x;
  const int w = tid >> 6, l = tid & 63, lg = l >> 4, lr = l & 15;
  const int wm = (w >> 1) * 2, wn = (w & 1) * 2;
  const int sr = tid >> 2, sc = (tid & 3) * 8;
  f32x4 acc[2][2] = {};
  for (int k0 = 0; k0 < 1024; k0 += 32) {
    *(bf16x8*)&As[sr][sc] = *(const bf16x8*)(A + (size_t)(m0 + sr) * 1024 + k0 + sc);
    *(bf16x8*)&Bs[sr][sc] = *(const bf16x8*)(WT + (size_t)(n0 + sr) * 1024 + k0 + sc);
    __syncthreads();
    bf16x8 af[2], bfr[2];
#pragma unroll
    for (int mi = 0; mi < 2; ++mi) af[mi] = *(const bf16x8*)&As[(wm + mi) * 16 + lr][lg * 8];
#pragma unroll
    for (int ni = 0; ni < 2; ++ni) bfr[ni] = *(const bf16x8*)&Bs[(wn + ni) * 16 + lr][lg * 8];
#pragma unroll
    for (int mi = 0; mi < 2; ++mi)
#pragma unroll
      for (int ni = 0; ni < 2; ++ni) acc[mi][ni] = MFMA(af[mi], bfr[ni], acc[mi][ni]);
    __syncthreads();
  }
#pragma unroll
  for (int mi = 0; mi < 2; ++mi)
#pragma unroll
    for (int ni = 0; ni < 2; ++ni)
#pragma unroll
      for (int r = 0; r < 4; ++r) {
        int m = m0 + (wm + mi) * 16 + lg * 4 + r;
        int n = n0 + (wn + ni) * 16 + lr;
        float val = (acc[mi][ni][r] + bias[n]) * scale;
        int b = m >> 10, t = m & 1023, h = n >> 6, dk = n & 63;
        out[((size_t)(b * 16 + h) * 1024 + t) * 64 + dk] = f2b(val);
      }
}

// K1T: same, stores transposed per head: vT[bh][dk][t].
__global__ __launch_bounds__(256) void k_projT(
    const short* __restrict__ A, const short* __restrict__ WT,
    const float* __restrict__ bias, short* __restrict__ out) {
  __shared__ short As[64][40];
  __shared__ short Bs[64][40];
  const int n0 = blockIdx.x * 64, m0 = blockIdx.y * 64;
  const int tid = threadIdx.x;
  const int w = tid >> 6, l = tid & 63, lg = l >> 4, lr = l & 15;
  const int wm = (w >> 1) * 2, wn = (w & 1) * 2;
  const int sr = tid >> 2, sc = (tid & 3) * 8;
  f32x4 acc[2][2] = {};
  for (int k0 = 0; k0 < 1024; k0 += 32) {
    *(bf16x8*)&As[sr][sc] = *(const bf16x8*)(A + (size_t)(m0 + sr) * 1024 + k0 + sc);
    *(bf16x8*)&Bs[sr][sc] = *(const bf16x8*)(WT + (size_t)(n0 + sr) * 1024 + k0 + sc);
    __syncthreads();
    bf16x8 af[2], bfr[2];
#pragma unroll
    for (int mi = 0; mi < 2; ++mi) af[mi] = *(const bf16x8*)&As[(wm + mi) * 16 + lr][lg * 8];
#pragma unroll
    for (int ni = 0; ni < 2; ++ni) bfr[ni] = *(const bf16x8*)&Bs[(wn + ni) * 16 + lr][lg * 8];
#pragma unroll
    for (int mi = 0; mi < 2; ++mi)
#pragma unroll
      for (int ni = 0; ni < 2; ++ni) acc[mi][ni] = MFMA(af[mi], bfr[ni], acc[mi][ni]);
    __syncthreads();
  }
#pragma unroll
  for (int mi = 0; mi < 2; ++mi)
#pragma unroll
    for (int ni = 0; ni < 2; ++ni)
#pragma unroll
      for (int r = 0; r < 4; ++r) {
        int m = m0 + (wm + mi) * 16 + lg * 4 + r;
        int n = n0 + (wn + ni) * 16 + lr;
        float val = acc[mi][ni][r] + bias[n];
        int b = m >> 10, t = m & 1023, h = n >> 6, dk = n & 63;
        out[(((size_t)(b * 16 + h) * 64 + dk) << 10) + t] = f2b(val);
      }
}

// ---------------------------------------------------------------------------
// K2a: S[bh,t,s] = q·pos_k + bias (+mask). Epilogue bounced through per-wave
// LDS tile -> 4x bf16x8 stores (1 KB/wave-inst).
__global__ __launch_bounds__(256) void k_posk_bias(
    const short* __restrict__ q, const float* __restrict__ pos_k,
    const float* __restrict__ rab, const int* __restrict__ mask,
    short* __restrict__ S) {
  const int t = blockIdx.y;
  const int tid = threadIdx.x;
  const int w = tid >> 6, l = tid & 63, lg = l >> 4, lr = l & 15;
  const int s0 = blockIdx.x * 256 + w * 64;
  __shared__ short LW[4][32][74];
  bf16x8 af[2][2];
#pragma unroll
  for (int mi = 0; mi < 2; ++mi)
#pragma unroll
    for (int kk = 0; kk < 2; ++kk) {
      int bh = mi * 16 + lr;
      af[mi][kk] = *(const bf16x8*)(q + ((size_t)bh * 1024 + t) * 64 + kk * 32 + lg * 8);
    }
  f32x4 acc[2][4] = {};
#pragma unroll
  for (int ni = 0; ni < 4; ++ni) {
    int s = s0 + ni * 16 + lr;
#pragma unroll
    for (int kk = 0; kk < 2; ++kk) {
      const float* pk = pos_k + ((size_t)t * 1024 + s) * 64 + kk * 32 + lg * 8;
      const float4 p0 = *(const float4*)pk;
      const float4 p1 = *(const float4*)(pk + 4);
      bf16x8 bfr;
      bfr[0] = f2b(p0.x); bfr[1] = f2b(p0.y); bfr[2] = f2b(p0.z); bfr[3] = f2b(p0.w);
      bfr[4] = f2b(p1.x); bfr[5] = f2b(p1.y); bfr[6] = f2b(p1.z); bfr[7] = f2b(p1.w);
#pragma unroll
      for (int mi = 0; mi < 2; ++mi) acc[mi][ni] = MFMA(af[mi][kk], bfr, acc[mi][ni]);
    }
  }
#pragma unroll
  for (int ni = 0; ni < 4; ++ni) {
    int s = s0 + ni * 16 + lr;
    int msk0 = mask[(size_t)t * 1024 + s];
    int msk1 = mask[(size_t)(1024 + t) * 1024 + s];
#pragma unroll
    for (int r = 0; r < 4; ++r) {
      int h = lg * 4 + r;
      float bv = rab[((size_t)h * 1024 + t) * 1024 + s];
      float v0 = acc[0][ni][r] + bv;
      float v1 = acc[1][ni][r] + bv;
      if (msk0 == 0) v0 = -1e30f;
      if (msk1 == 0) v1 = -1e30f;
      LW[w][h][ni * 16 + lr] = f2b(v0);
      LW[w][16 + h][ni * 16 + lr] = f2b(v1);
    }
  }
  // per-wave tile: no barrier needed, lgkmcnt dependency only
#pragma unroll
  for (int rr = 0; rr < 4; ++rr) {
    int row = (l >> 3) + rr * 8;  // row == bh (b=row>>4, h=row&15)
    int s8 = (l & 7) * 8;
    bf16x8 o = *(const bf16x8*)&LW[w][row][s8];
    *(bf16x8*)(S + ((size_t)row * 1024 + t) * 1024 + s0 + s8) = o;
  }
}

// ---------------------------------------------------------------------------
// K2b: S = softmax_rows(q@k^T + S) in place. grid (T/32, bh); 8 waves.
// S tile staged per-wave in LDS: vector global I/O, scalar LDS access.
__global__ __launch_bounds__(512, 4) void k_attn_softmax(
    const short* __restrict__ q, const short* __restrict__ kmat,
    short* __restrict__ S) {
  const int bh = blockIdx.y;
  const int tid = threadIdx.x;
  const int w = tid >> 6, l = tid & 63, lg = l >> 4, lr = l & 15;
  const int wm = w >> 2, wn = w & 3;
  const int t0 = blockIdx.x * 32 + wm * 16;
  const int scol = wn * 256;
  __shared__ short LS[8][16][266];
  __shared__ float redA[32][4];
  __shared__ float redB[32][4];

  // stage this wave's 16x256 S tile (vector loads)
  short* sb = (short*)(S + ((size_t)bh * 1024 + t0) * 1024 + scol);
  const int r2 = l >> 5, c16 = (l & 31) * 8;
#pragma unroll
  for (int rr = 0; rr < 8; ++rr) {
    int row = rr * 2 + r2;
    *(bf16x8*)&LS[w][row][c16] = *(const bf16x8*)(sb + (size_t)row * 1024 + c16);
  }

  bf16x8 af[2];
#pragma unroll
  for (int kk = 0; kk < 2; ++kk)
    af[kk] = *(const bf16x8*)(q + ((size_t)bh * 1024 + (t0 + lr)) * 64 + kk * 32 + lg * 8);

  f32x4 acc[16];
#pragma unroll
  for (int ni = 0; ni < 16; ++ni) {
    int s = scol + ni * 16 + lr;
    const short* kp = kmat + ((size_t)bh * 1024 + s) * 64 + lg * 8;
    bf16x8 b0 = *(const bf16x8*)kp;
    bf16x8 b1 = *(const bf16x8*)(kp + 32);
    f32x4 a = {};
    a = MFMA(af[0], b0, a);
    a = MFMA(af[1], b1, a);
    acc[ni] = a;
  }
#pragma unroll
  for (int ni = 0; ni < 16; ++ni)
#pragma unroll
    for (int r = 0; r < 4; ++r) acc[ni][r] += b2f(LS[w][lg * 4 + r][ni * 16 + lr]);

  float pm[4];
#pragma unroll
  for (int r = 0; r < 4; ++r) {
    float m = acc[0][r];
#pragma unroll
    for (int ni = 1; ni < 16; ++ni) m = fmaxf(m, acc[ni][r]);
    m = fmaxf(m, __shfl_xor(m, 1));
    m = fmaxf(m, __shfl_xor(m, 2));
    m = fmaxf(m, __shfl_xor(m, 4));
    m = fmaxf(m, __shfl_xor(m, 8));
    pm[r] = m;
  }
  if (lr == 0) {
#pragma unroll
    for (int r = 0; r < 4; ++r) redA[wm * 16 + lg * 4 + r][wn] = pm[r];
  }
  __syncthreads();
  float rowm[4];
#pragma unroll
  for (int r = 0; r < 4; ++r) {
    int row = wm * 16 + lg * 4 + r;
    rowm[r] = fmaxf(fmaxf(redA[row][0], redA[row][1]), fmaxf(redA[row][2], redA[row][3]));
  }
  float rs[4];
#pragma unroll
  for (int r = 0; r < 4; ++r) {
    float sum = 0.f;
#pragma unroll
    for (int ni = 0; ni < 16; ++ni) {
      float e = __expf(acc[ni][r] - rowm[r]);
      acc[ni][r] = e;
      sum += e;
    }
    sum += __shfl_xor(sum, 1);
    sum += __shfl_xor(sum, 2);
    sum += __shfl_xor(sum, 4);
    sum += __shfl_xor(sum, 8);
    rs[r] = sum;
  }
  if (lr == 0) {
#pragma unroll
    for (int r = 0; r < 4; ++r) redB[wm * 16 + lg * 4 + r][wn] = rs[r];
  }
  __syncthreads();
#pragma unroll
  for (int r = 0; r < 4; ++r) {
    int row = wm * 16 + lg * 4 + r;
    float inv = 1.0f / (redB[row][0] + redB[row][1] + redB[row][2] + redB[row][3]);
#pragma unroll
    for (int ni = 0; ni < 16; ++ni) LS[w][lg * 4 + r][ni * 16 + lr] = f2b(acc[ni][r] * inv);
  }
  // write back (vector stores); per-wave tile, no barrier needed
#pragma unroll
  for (int rr = 0; rr < 8; ++rr) {
    int row = rr * 2 + r2;
    bf16x8 o = *(const bf16x8*)&LS[w][row][c16];
    *(bf16x8*)(sb + (size_t)row * 1024 + c16) = o;
  }
}

// ---------------------------------------------------------------------------
// K3: X0h = bf16(attn @ pos_v[t]). grid (T); 4 waves.
__global__ __launch_bounds__(256) void k_posv(
    const short* __restrict__ S, const float* __restrict__ pos_v,
    short* __restrict__ X0h) {
  const int t = blockIdx.x;
  const int tid = threadIdx.x;
  const int w = tid >> 6, l = tid & 63, lg = l >> 4, lr = l & 15;
  const int mi = w >> 1;
  const int nb = (w & 1) * 2;
  __shared__ short pv[256][66];
  f32x4 acc[2] = {};
  const int srow = tid >> 4;
  const int dk4 = (tid & 15) * 4;
  for (int c = 0; c < 4; ++c) {
    int sc = c * 256;
    if (c) __syncthreads();
#pragma unroll
    for (int it = 0; it < 16; ++it) {
      int s = srow + it * 16;
      float4 p = *(const float4*)(pos_v + ((size_t)t * 1024 + sc + s) * 64 + dk4);
      unsigned p0 = (unsigned)(unsigned short)f2b(p.x) | ((unsigned)(unsigned short)f2b(p.y) << 16);
      unsigned p1 = (unsigned)(unsigned short)f2b(p.z) | ((unsigned)(unsigned short)f2b(p.w) << 16);
      *(unsigned*)&pv[s][dk4] = p0;
      *(unsigned*)&pv[s][dk4 + 2] = p1;
    }
    __syncthreads();
    const int bh = mi * 16 + lr;
#pragma unroll
    for (int kk = 0; kk < 8; ++kk) {
      bf16x8 afr = *(const bf16x8*)(S + ((size_t)bh * 1024 + t) * 1024 + sc + kk * 32 + lg * 8);
#pragma unroll
      for (int ni = 0; ni < 2; ++ni) {
        int dk = (nb + ni) * 16 + lr;
        bf16x8 bfr;
#pragma unroll
        for (int j = 0; j < 8; ++j) bfr[j] = pv[kk * 32 + lg * 8 + j][dk];
        acc[ni] = MFMA(afr, bfr, acc[ni]);
      }
    }
  }
#pragma unroll
  for (int ni = 0; ni < 2; ++ni)
#pragma unroll
    for (int r = 0; r < 4; ++r) {
      int bh = mi * 16 + lg * 4 + r;
      int b = bh >> 4, h = bh & 15;
      int dk = (nb + ni) * 16 + lr;
      X0h[((size_t)(b * 1024 + t)) * 1024 + h * 64 + dk] = f2b(acc[ni][r]);
    }
}

// ---------------------------------------------------------------------------
// K4: X = bf16(X0h + attn @ v). grid (T/128, bh); no LDS (vT from L2).
__global__ __launch_bounds__(256) void k_av(
    const short* __restrict__ S, const short* __restrict__ vT,
    const short* __restrict__ X0h, short* __restrict__ X) {
  const int bh = blockIdx.y;
  const int tt0 = blockIdx.x * 128;
  const int tid = threadIdx.x;
  const int w = tid >> 6, l = tid & 63, lg = l >> 4, lr = l & 15;
  const short* vbase = vT + ((size_t)bh << 16);
  const short* sbase = S + ((size_t)bh << 20);
  f32x4 acc[2][4] = {};
#pragma unroll 4
  for (int kk = 0; kk < 32; ++kk) {
    bf16x8 afr[2];
#pragma unroll
    for (int mi = 0; mi < 2; ++mi) {
      int tt = tt0 + (w * 2 + mi) * 16 + lr;
      afr[mi] = *(const bf16x8*)(sbase + ((size_t)tt << 10) + kk * 32 + lg * 8);
    }
#pragma unroll
    for (int ni = 0; ni < 4; ++ni) {
      bf16x8 bfr = *(const bf16x8*)(vbase + ((ni * 16 + lr) << 10) + kk * 32 + lg * 8);
#pragma unroll
      for (int mi = 0; mi < 2; ++mi) acc[mi][ni] = MFMA(afr[mi], bfr, acc[mi][ni]);
    }
  }
  const int b = bh >> 4, h = bh & 15;
#pragma unroll
  for (int mi = 0; mi < 2; ++mi)
#pragma unroll
    for (int ni = 0; ni < 4; ++ni)
#pragma unroll
      for (int r = 0; r < 4; ++r) {
        int tt = tt0 + (w * 2 + mi) * 16 + lg * 4 + r;
        int d = h * 64 + ni * 16 + lr;
        size_t idx = ((size_t)(b * 1024 + tt)) * 1024 + d;
        X[idx] = f2b(b2f(X0h[idx]) + acc[mi][ni][r]);
      }
}

// ---------------------------------------------------------------------------
// K5: out = X @ Wo + bo (fp32 out), WT pre-transposed bf16.
__global__ __launch_bounds__(256) void k_oproj(
    const short* __restrict__ X, const short* __restrict__ WT,
    const float* __restrict__ bias, float* __restrict__ out) {
  __shared__ short As[64][40];
  __shared__ short Bs[64][40];
  const int n0 = blockIdx.x * 64, m0 = blockIdx.y * 64;
  const int tid = threadIdx.x;
  const int w = tid >> 6, l = tid & 63, lg = l >> 4, lr = l & 15;
  const int wm = (w >> 1) * 2, wn = (w & 1) * 2;
  const int sr = tid >> 2, sc = (tid & 3) * 8;
  f32x4 acc[2][2] = {};
  for (int k0 = 0; k0 < 1024; k0 += 32) {
    *(bf16x8*)&As[sr][sc] = *(const bf16x8*)(X + (size_t)(m0 + sr) * 1024 + k0 + sc);
    *(bf16x8*)&Bs[sr][sc] = *(const bf16x8*)(WT + (size_t)(n0 + sr) * 1024 + k0 + sc);
    __syncthreads();
    bf16x8 af[2], bfr[2];
#pragma unroll
    for (int mi = 0; mi < 2; ++mi) af[mi] = *(const bf16x8*)&As[(wm + mi) * 16 + lr][lg * 8];
#pragma unroll
    for (int ni = 0; ni < 2; ++ni) bfr[ni] = *(const bf16x8*)&Bs[(wn + ni) * 16 + lr][lg * 8];
#pragma unroll
    for (int mi = 0; mi < 2; ++mi)
#pragma unroll
      for (int ni = 0; ni < 2; ++ni) acc[mi][ni] = MFMA(af[mi], bfr[ni], acc[mi][ni]);
    __syncthreads();
  }
#pragma unroll
  for (int mi = 0; mi < 2; ++mi)
#pragma unroll
    for (int ni = 0; ni < 2; ++ni)
#pragma unroll
      for (int r = 0; r < 4; ++r) {
        int m = m0 + (wm + mi) * 16 + lg * 4 + r;
        int n = n0 + (wn + ni) * 16 + lr;
        out[(size_t)m * 1024 + n] = acc[mi][ni][r] + bias[n];
      }
}

// ---------------------------------------------------------------------------
extern "C" void kernel_launch(void* const* d_in, const int* in_sizes, int n_in,
                              void* d_out, int out_size, void* d_ws, size_t ws_size,
                              hipStream_t stream) {
  (void)in_sizes; (void)n_in; (void)out_size; (void)ws_size;
  const float* query = (const float*)d_in[0];
  const float* key   = (const float*)d_in[1];
  const float* value = (const float*)d_in[2];
  const float* pos_k = (const float*)d_in[3];
  const float* pos_v = (const float*)d_in[4];
  const int*   mask  = (const int*)d_in[5];
  const float* rab   = (const float*)d_in[6];
  const float* Wq = (const float*)d_in[7];
  const float* bq = (const float*)d_in[8];
  const float* Wk = (const float*)d_in[9];
  const float* bk = (const float*)d_in[10];
  const float* Wv = (const float*)d_in[11];
  const float* bv = (const float*)d_in[12];
  const float* Wo = (const float*)d_in[13];
  const float* bo = (const float*)d_in[14];
  float* out = (float*)d_out;

  const size_t M2 = 2ull * 1024 * 1024;  // B*T*D elements
  short* q   = (short*)d_ws;
  short* k   = q + M2;
  short* vT  = k + M2;                    // [bh][dk][t]
  short* S   = vT + M2;                   // 32M bf16 (B,H,T,T)
  short* X0h = S + 32ull * 1024 * 1024;
  short* X   = X0h + M2;
  short* qin = X + M2;
  short* kin = qin + M2;
  short* vin = kin + M2;
  short* WqT = vin + M2;
  short* WkT = WqT + 1024 * 1024;
  short* WvT = WkT + 1024 * 1024;
  short* WoT = WvT + 1024 * 1024;

  k_cvt3<<<dim3(1024, 3), dim3(256), 0, stream>>>(query, key, value, qin, kin, vin);
  k_wtrans4<<<dim3(16, 16, 4), dim3(256), 0, stream>>>(Wq, Wk, Wv, Wo, WqT, WkT, WvT, WoT);
  k_proj<<<dim3(16, 32), dim3(256), 0, stream>>>(qin, WqT, bq, q, 0.125f);
  k_proj<<<dim3(16, 32), dim3(256), 0, stream>>>(kin, WkT, bk, k, 1.0f);
  k_projT<<<dim3(16, 32), dim3(256), 0, stream>>>(vin, WvT, bv, vT);
  k_posk_bias<<<dim3(4, 1024), dim3(256), 0, stream>>>(q, pos_k, rab, mask, S);
  k_attn_softmax<<<dim3(32, 32), dim3(512), 0, stream>>>(q, k, S);
  k_posv<<<dim3(1024), dim3(256), 0, stream>>>(S, pos_v, X0h);
  k_av<<<dim3(8, 32), dim3(256), 0, stream>>>(S, vT, X0h, X);
  k_oproj<<<dim3(16, 32), dim3(256), 0, stream>>>(X, WoT, bo, out);
}

// Round 5
// 306.902 us; speedup vs baseline: 1.3772x; 1.0403x over previous
//
#include <hip/hip_runtime.h>

// MultiHeadedAttention with relative position (B=2, T=1024, D=1024, H=16, DK=64)
// Pipeline: cvt(inputs->bf16), wtrans(W->bf16 [n][k]) -> fused QKV GEMM (128^2,
// global_load_lds) -> S=Bp+bias+mask -> S=softmax(qk^T+S) in-place ->
// X0=attn@pos_v -> X=X0+attn@v -> out=X@Wo+bo (128^2).

#define DEV __device__ __forceinline__

typedef short bf16x8 __attribute__((ext_vector_type(8)));
typedef float f32x4 __attribute__((ext_vector_type(4)));

DEV short f2b(float f) {
  unsigned u = __builtin_bit_cast(unsigned, f);
  u = (u + 0x7FFFu + ((u >> 16) & 1u)) >> 16;
  return (short)u;
}
DEV float b2f(short s) {
  unsigned u = ((unsigned)(unsigned short)s) << 16;
  return __builtin_bit_cast(float, u);
}

#define MFMA(a, b, c) __builtin_amdgcn_mfma_f32_16x16x32_bf16(a, b, c, 0, 0, 0)

// async global->LDS, 16B per lane: dest must be WAVE-UNIFORM base (+lane*16 HW),
// source is per-lane.
DEV void gload16(const void* g, void* l) {
  __builtin_amdgcn_global_load_lds(
      (const __attribute__((address_space(1))) void*)g,
      (__attribute__((address_space(3))) void*)l, 16, 0, 0);
}

// ---------------------------------------------------------------------------
// P1: fp32 -> bf16 flat convert for query/key/value (2M elems each).
__global__ __launch_bounds__(256) void k_cvt3(
    const float* __restrict__ a, const float* __restrict__ b, const float* __restrict__ c,
    short* __restrict__ oa, short* __restrict__ ob, short* __restrict__ oc) {
  const float* src = blockIdx.y == 0 ? a : (blockIdx.y == 1 ? b : c);
  short* dst = blockIdx.y == 0 ? oa : (blockIdx.y == 1 ? ob : oc);
  size_t i = ((size_t)blockIdx.x * 256 + threadIdx.x) * 8;
  float4 p0 = *(const float4*)(src + i);
  float4 p1 = *(const float4*)(src + i + 4);
  bf16x8 o;
  o[0] = f2b(p0.x); o[1] = f2b(p0.y); o[2] = f2b(p0.z); o[3] = f2b(p0.w);
  o[4] = f2b(p1.x); o[5] = f2b(p1.y); o[6] = f2b(p1.z); o[7] = f2b(p1.w);
  *(bf16x8*)(dst + i) = o;
}

// P2: W [k][n] fp32 -> WT [n][k] bf16, 64x64 tiles via LDS.
__global__ __launch_bounds__(256) void k_wtrans4(
    const float* __restrict__ w0, const float* __restrict__ w1,
    const float* __restrict__ w2, const float* __restrict__ w3,
    short* __restrict__ o0, short* __restrict__ o1,
    short* __restrict__ o2, short* __restrict__ o3) {
  const float* src; short* dst;
  switch (blockIdx.z) {
    case 0: src = w0; dst = o0; break;
    case 1: src = w1; dst = o1; break;
    case 2: src = w2; dst = o2; break;
    default: src = w3; dst = o3;
  }
  __shared__ short LW[64][74];
  const int tid = threadIdx.x;
  const int k0 = blockIdx.y * 64, n0 = blockIdx.x * 64;
  {
    int c4 = (tid & 15) * 4;
#pragma unroll
    for (int i = 0; i < 4; ++i) {
      int r = (tid >> 4) + i * 16;
      float4 v = *(const float4*)(src + (size_t)(k0 + r) * 1024 + n0 + c4);
      LW[r][c4 + 0] = f2b(v.x); LW[r][c4 + 1] = f2b(v.y);
      LW[r][c4 + 2] = f2b(v.z); LW[r][c4 + 3] = f2b(v.w);
    }
  }
  __syncthreads();
  {
    int n = tid >> 2, kb = (tid & 3) * 16;
#pragma unroll
    for (int j2 = 0; j2 < 2; ++j2) {
      int kk = kb + j2 * 8;
      bf16x8 o;
#pragma unroll
      for (int j = 0; j < 8; ++j) o[j] = LW[kk + j][n];
      *(bf16x8*)(dst + (size_t)(n0 + n) * 1024 + k0 + kk) = o;
    }
  }
}

// ---------------------------------------------------------------------------
// K1: fused QKV projection. A = stacked [3][2048][1024] bf16 (qin,kin,vin),
// WT = stacked [3][1024][1024] bf16. 128x128 tile, BK=32, 4 waves (2x2),
// 4x4 fragments/wave, global_load_lds staging, LDS-bounced epilogue.
// seg 0 -> q (scaled 1/8, [bh][t][dk]); seg 1 -> k; seg 2 -> vT [bh][dk][t].
__global__ __launch_bounds__(256) void k_qkv(
    const short* __restrict__ Ain, const short* __restrict__ WT,
    const float* __restrict__ bq, const float* __restrict__ bk,
    const float* __restrict__ bv,
    short* __restrict__ qo, short* __restrict__ ko, short* __restrict__ vTo) {
  __shared__ short As[128 * 32];
  __shared__ short Bs[128 * 32];
  __shared__ short LW[128][136];  // 128 data cols + 8 pad (R4 bug: was [72])
  const int tid = threadIdx.x;
  const int w = tid >> 6, l = tid & 63, lg = l >> 4, lr = l & 15;
  const int wm = w >> 1, wn = w & 1;
  const int n0 = blockIdx.x * 128;
  const int m0 = blockIdx.y * 128;     // global stacked row
  const int seg = m0 >> 11;
  const int mseg = m0 & 2047;
  const short* Abase = Ain + ((size_t)m0 << 10);
  const short* Bbase = WT + ((size_t)seg << 20) + ((size_t)n0 << 10);
  const int srow = l >> 2, scol8 = (l & 3) * 8;   // lane source mapping
  f32x4 acc[4][4] = {};
  for (int k0 = 0; k0 < 1024; k0 += 32) {
#pragma unroll
    for (int c = 0; c < 2; ++c) {
      int chunk = w * 2 + c;                       // 16-row chunk
      int row = chunk * 16 + srow;
      gload16(Abase + (size_t)row * 1024 + k0 + scol8, &As[chunk * 512]);
      gload16(Bbase + (size_t)row * 1024 + k0 + scol8, &Bs[chunk * 512]);
    }
    __syncthreads();
    bf16x8 af[4], bf[4];
#pragma unroll
    for (int i = 0; i < 4; ++i) af[i] = *(const bf16x8*)&As[(wm * 64 + i * 16 + lr) * 32 + lg * 8];
#pragma unroll
    for (int i = 0; i < 4; ++i) bf[i] = *(const bf16x8*)&Bs[(wn * 64 + i * 16 + lr) * 32 + lg * 8];
#pragma unroll
    for (int mi = 0; mi < 4; ++mi)
#pragma unroll
      for (int ni = 0; ni < 4; ++ni) acc[mi][ni] = MFMA(af[mi], bf[ni], acc[mi][ni]);
    __syncthreads();
  }
  const float* bias = seg == 0 ? bq : (seg == 1 ? bk : bv);
  const float scale = seg == 0 ? 0.125f : 1.0f;
  float bvals[4];
#pragma unroll
  for (int ni = 0; ni < 4; ++ni) bvals[ni] = bias[n0 + wn * 64 + ni * 16 + lr];
#pragma unroll
  for (int mi = 0; mi < 4; ++mi)
#pragma unroll
    for (int ni = 0; ni < 4; ++ni)
#pragma unroll
      for (int r = 0; r < 4; ++r)
        LW[wm * 64 + mi * 16 + lg * 4 + r][wn * 64 + ni * 16 + lr] =
            f2b((acc[mi][ni][r] + bvals[ni]) * scale);
  __syncthreads();
  if (seg < 2) {
    short* dst = seg == 0 ? qo : ko;
    int r = tid >> 1, half = tid & 1;
    int m = mseg + r, b = m >> 10, t = m & 1023;
#pragma unroll
    for (int g = 0; g < 8; ++g) {
      int n = n0 + half * 64 + g * 8;
      int h = n >> 6, dk = n & 63;
      bf16x8 o = *(const bf16x8*)&LW[r][half * 64 + g * 8];
      *(bf16x8*)(dst + (((size_t)(b * 16 + h) * 1024 + t) << 6) + dk) = o;
    }
  } else {
    int dkc = tid & 127, th = tid >> 7;
    int n = n0 + dkc, h = n >> 6, dk = n & 63;
    int b = mseg >> 10;
    int tbase = (mseg & 1023) + th * 64;
#pragma unroll
    for (int g = 0; g < 8; ++g) {
      bf16x8 o;
#pragma unroll
      for (int e = 0; e < 8; ++e) o[e] = LW[th * 64 + g * 8 + e][dkc];
      *(bf16x8*)(vTo + (((size_t)(b * 16 + h) * 64 + dk) << 10) + tbase + g * 8) = o;
    }
  }
}

// ---------------------------------------------------------------------------
// K2a: S[bh,t,s] = q·pos_k + bias (+mask). Epilogue bounced through per-wave
// LDS tile -> 4x bf16x8 stores.
__global__ __launch_bounds__(256) void k_posk_bias(
    const short* __restrict__ q, const float* __restrict__ pos_k,
    const float* __restrict__ rab, const int* __restrict__ mask,
    short* __restrict__ S) {
  const int t = blockIdx.y;
  const int tid = threadIdx.x;
  const int w = tid >> 6, l = tid & 63, lg = l >> 4, lr = l & 15;
  const int s0 = blockIdx.x * 256 + w * 64;
  __shared__ short LW[4][32][74];
  bf16x8 af[2][2];
#pragma unroll
  for (int mi = 0; mi < 2; ++mi)
#pragma unroll
    for (int kk = 0; kk < 2; ++kk) {
      int bh = mi * 16 + lr;
      af[mi][kk] = *(const bf16x8*)(q + ((size_t)bh * 1024 + t) * 64 + kk * 32 + lg * 8);
    }
  f32x4 acc[2][4] = {};
#pragma unroll
  for (int ni = 0; ni < 4; ++ni) {
    int s = s0 + ni * 16 + lr;
#pragma unroll
    for (int kk = 0; kk < 2; ++kk) {
      const float* pk = pos_k + ((size_t)t * 1024 + s) * 64 + kk * 32 + lg * 8;
      const float4 p0 = *(const float4*)pk;
      const float4 p1 = *(const float4*)(pk + 4);
      bf16x8 bfr;
      bfr[0] = f2b(p0.x); bfr[1] = f2b(p0.y); bfr[2] = f2b(p0.z); bfr[3] = f2b(p0.w);
      bfr[4] = f2b(p1.x); bfr[5] = f2b(p1.y); bfr[6] = f2b(p1.z); bfr[7] = f2b(p1.w);
#pragma unroll
      for (int mi = 0; mi < 2; ++mi) acc[mi][ni] = MFMA(af[mi][kk], bfr, acc[mi][ni]);
    }
  }
#pragma unroll
  for (int ni = 0; ni < 4; ++ni) {
    int s = s0 + ni * 16 + lr;
    int msk0 = mask[(size_t)t * 1024 + s];
    int msk1 = mask[(size_t)(1024 + t) * 1024 + s];
#pragma unroll
    for (int r = 0; r < 4; ++r) {
      int h = lg * 4 + r;
      float bv = rab[((size_t)h * 1024 + t) * 1024 + s];
      float v0 = acc[0][ni][r] + bv;
      float v1 = acc[1][ni][r] + bv;
      if (msk0 == 0) v0 = -1e30f;
      if (msk1 == 0) v1 = -1e30f;
      LW[w][h][ni * 16 + lr] = f2b(v0);
      LW[w][16 + h][ni * 16 + lr] = f2b(v1);
    }
  }
#pragma unroll
  for (int rr = 0; rr < 4; ++rr) {
    int row = (l >> 3) + rr * 8;  // row == bh
    int s8 = (l & 7) * 8;
    bf16x8 o = *(const bf16x8*)&LW[w][row][s8];
    *(bf16x8*)(S + ((size_t)row * 1024 + t) * 1024 + s0 + s8) = o;
  }
}

// ---------------------------------------------------------------------------
// K2b: S = softmax_rows(q@k^T + S) in place. grid (T/32, bh); 8 waves.
__global__ __launch_bounds__(512, 4) void k_attn_softmax(
    const short* __restrict__ q, const short* __restrict__ kmat,
    short* __restrict__ S) {
  const int bh = blockIdx.y;
  const int tid = threadIdx.x;
  const int w = tid >> 6, l = tid & 63, lg = l >> 4, lr = l & 15;
  const int wm = w >> 2, wn = w & 3;
  const int t0 = blockIdx.x * 32 + wm * 16;
  const int scol = wn * 256;
  __shared__ short LS[8][16][266];
  __shared__ float redA[32][4];
  __shared__ float redB[32][4];

  short* sb = (short*)(S + ((size_t)bh * 1024 + t0) * 1024 + scol);
  const int r2 = l >> 5, c16 = (l & 31) * 8;
#pragma unroll
  for (int rr = 0; rr < 8; ++rr) {
    int row = rr * 2 + r2;
    *(bf16x8*)&LS[w][row][c16] = *(const bf16x8*)(sb + (size_t)row * 1024 + c16);
  }

  bf16x8 af[2];
#pragma unroll
  for (int kk = 0; kk < 2; ++kk)
    af[kk] = *(const bf16x8*)(q + ((size_t)bh * 1024 + (t0 + lr)) * 64 + kk * 32 + lg * 8);

  f32x4 acc[16];
#pragma unroll
  for (int ni = 0; ni < 16; ++ni) {
    int s = scol + ni * 16 + lr;
    const short* kp = kmat + ((size_t)bh * 1024 + s) * 64 + lg * 8;
    bf16x8 b0 = *(const bf16x8*)kp;
    bf16x8 b1 = *(const bf16x8*)(kp + 32);
    f32x4 a = {};
    a = MFMA(af[0], b0, a);
    a = MFMA(af[1], b1, a);
    acc[ni] = a;
  }
#pragma unroll
  for (int ni = 0; ni < 16; ++ni)
#pragma unroll
    for (int r = 0; r < 4; ++r) acc[ni][r] += b2f(LS[w][lg * 4 + r][ni * 16 + lr]);

  float pm[4];
#pragma unroll
  for (int r = 0; r < 4; ++r) {
    float m = acc[0][r];
#pragma unroll
    for (int ni = 1; ni < 16; ++ni) m = fmaxf(m, acc[ni][r]);
    m = fmaxf(m, __shfl_xor(m, 1));
    m = fmaxf(m, __shfl_xor(m, 2));
    m = fmaxf(m, __shfl_xor(m, 4));
    m = fmaxf(m, __shfl_xor(m, 8));
    pm[r] = m;
  }
  if (lr == 0) {
#pragma unroll
    for (int r = 0; r < 4; ++r) redA[wm * 16 + lg * 4 + r][wn] = pm[r];
  }
  __syncthreads();
  float rowm[4];
#pragma unroll
  for (int r = 0; r < 4; ++r) {
    int row = wm * 16 + lg * 4 + r;
    rowm[r] = fmaxf(fmaxf(redA[row][0], redA[row][1]), fmaxf(redA[row][2], redA[row][3]));
  }
  float rs[4];
#pragma unroll
  for (int r = 0; r < 4; ++r) {
    float sum = 0.f;
#pragma unroll
    for (int ni = 0; ni < 16; ++ni) {
      float e = __expf(acc[ni][r] - rowm[r]);
      acc[ni][r] = e;
      sum += e;
    }
    sum += __shfl_xor(sum, 1);
    sum += __shfl_xor(sum, 2);
    sum += __shfl_xor(sum, 4);
    sum += __shfl_xor(sum, 8);
    rs[r] = sum;
  }
  if (lr == 0) {
#pragma unroll
    for (int r = 0; r < 4; ++r) redB[wm * 16 + lg * 4 + r][wn] = rs[r];
  }
  __syncthreads();
#pragma unroll
  for (int r = 0; r < 4; ++r) {
    int row = wm * 16 + lg * 4 + r;
    float inv = 1.0f / (redB[row][0] + redB[row][1] + redB[row][2] + redB[row][3]);
#pragma unroll
    for (int ni = 0; ni < 16; ++ni) LS[w][lg * 4 + r][ni * 16 + lr] = f2b(acc[ni][r] * inv);
  }
#pragma unroll
  for (int rr = 0; rr < 8; ++rr) {
    int row = rr * 2 + r2;
    bf16x8 o = *(const bf16x8*)&LS[w][row][c16];
    *(bf16x8*)(sb + (size_t)row * 1024 + c16) = o;
  }
}

// ---------------------------------------------------------------------------
// K3: X0h = bf16(attn @ pos_v[t]). grid (T); 4 waves.
__global__ __launch_bounds__(256) void k_posv(
    const short* __restrict__ S, const float* __restrict__ pos_v,
    short* __restrict__ X0h) {
  const int t = blockIdx.x;
  const int tid = threadIdx.x;
  const int w = tid >> 6, l = tid & 63, lg = l >> 4, lr = l & 15;
  const int mi = w >> 1;
  const int nb = (w & 1) * 2;
  __shared__ short pv[256][66];
  f32x4 acc[2] = {};
  const int srow = tid >> 4;
  const int dk4 = (tid & 15) * 4;
  for (int c = 0; c < 4; ++c) {
    int sc = c * 256;
    if (c) __syncthreads();
#pragma unroll
    for (int it = 0; it < 16; ++it) {
      int s = srow + it * 16;
      float4 p = *(const float4*)(pos_v + ((size_t)t * 1024 + sc + s) * 64 + dk4);
      unsigned p0 = (unsigned)(unsigned short)f2b(p.x) | ((unsigned)(unsigned short)f2b(p.y) << 16);
      unsigned p1 = (unsigned)(unsigned short)f2b(p.z) | ((unsigned)(unsigned short)f2b(p.w) << 16);
      *(unsigned*)&pv[s][dk4] = p0;
      *(unsigned*)&pv[s][dk4 + 2] = p1;
    }
    __syncthreads();
    const int bh = mi * 16 + lr;
#pragma unroll
    for (int kk = 0; kk < 8; ++kk) {
      bf16x8 afr = *(const bf16x8*)(S + ((size_t)bh * 1024 + t) * 1024 + sc + kk * 32 + lg * 8);
#pragma unroll
      for (int ni = 0; ni < 2; ++ni) {
        int dk = (nb + ni) * 16 + lr;
        bf16x8 bfr;
#pragma unroll
        for (int j = 0; j < 8; ++j) bfr[j] = pv[kk * 32 + lg * 8 + j][dk];
        acc[ni] = MFMA(afr, bfr, acc[ni]);
      }
    }
  }
#pragma unroll
  for (int ni = 0; ni < 2; ++ni)
#pragma unroll
    for (int r = 0; r < 4; ++r) {
      int bh = mi * 16 + lg * 4 + r;
      int b = bh >> 4, h = bh & 15;
      int dk = (nb + ni) * 16 + lr;
      X0h[((size_t)(b * 1024 + t)) * 1024 + h * 64 + dk] = f2b(acc[ni][r]);
    }
}

// ---------------------------------------------------------------------------
// K4: X = bf16(X0h + attn @ v). grid (T/128, bh); no LDS (vT from L2).
__global__ __launch_bounds__(256) void k_av(
    const short* __restrict__ S, const short* __restrict__ vT,
    const short* __restrict__ X0h, short* __restrict__ X) {
  const int bh = blockIdx.y;
  const int tt0 = blockIdx.x * 128;
  const int tid = threadIdx.x;
  const int w = tid >> 6, l = tid & 63, lg = l >> 4, lr = l & 15;
  const short* vbase = vT + ((size_t)bh << 16);
  const short* sbase = S + ((size_t)bh << 20);
  f32x4 acc[2][4] = {};
#pragma unroll 4
  for (int kk = 0; kk < 32; ++kk) {
    bf16x8 afr[2];
#pragma unroll
    for (int mi = 0; mi < 2; ++mi) {
      int tt = tt0 + (w * 2 + mi) * 16 + lr;
      afr[mi] = *(const bf16x8*)(sbase + ((size_t)tt << 10) + kk * 32 + lg * 8);
    }
#pragma unroll
    for (int ni = 0; ni < 4; ++ni) {
      bf16x8 bfr = *(const bf16x8*)(vbase + ((ni * 16 + lr) << 10) + kk * 32 + lg * 8);
#pragma unroll
      for (int mi = 0; mi < 2; ++mi) acc[mi][ni] = MFMA(afr[mi], bfr, acc[mi][ni]);
    }
  }
  const int b = bh >> 4, h = bh & 15;
#pragma unroll
  for (int mi = 0; mi < 2; ++mi)
#pragma unroll
    for (int ni = 0; ni < 4; ++ni)
#pragma unroll
      for (int r = 0; r < 4; ++r) {
        int tt = tt0 + (w * 2 + mi) * 16 + lg * 4 + r;
        int d = h * 64 + ni * 16 + lr;
        size_t idx = ((size_t)(b * 1024 + tt)) * 1024 + d;
        X[idx] = f2b(b2f(X0h[idx]) + acc[mi][ni][r]);
      }
}

// ---------------------------------------------------------------------------
// K5: out = X @ Wo + bo (fp32). 128x128 tile, BK=32, global_load_lds, direct stores.
__global__ __launch_bounds__(256) void k_oproj(
    const short* __restrict__ X, const short* __restrict__ WT,
    const float* __restrict__ bias, float* __restrict__ out) {
  __shared__ short As[128 * 32];
  __shared__ short Bs[128 * 32];
  const int tid = threadIdx.x;
  const int w = tid >> 6, l = tid & 63, lg = l >> 4, lr = l & 15;
  const int wm = w >> 1, wn = w & 1;
  const int n0 = blockIdx.x * 128;
  const int m0 = blockIdx.y * 128;
  const short* Abase = X + ((size_t)m0 << 10);
  const short* Bbase = WT + ((size_t)n0 << 10);
  const int srow = l >> 2, scol8 = (l & 3) * 8;
  f32x4 acc[4][4] = {};
  for (int k0 = 0; k0 < 1024; k0 += 32) {
#pragma unroll
    for (int c = 0; c < 2; ++c) {
      int chunk = w * 2 + c;
      int row = chunk * 16 + srow;
      gload16(Abase + (size_t)row * 1024 + k0 + scol8, &As[chunk * 512]);
      gload16(Bbase + (size_t)row * 1024 + k0 + scol8, &Bs[chunk * 512]);
    }
    __syncthreads();
    bf16x8 af[4], bf[4];
#pragma unroll
    for (int i = 0; i < 4; ++i) af[i] = *(const bf16x8*)&As[(wm * 64 + i * 16 + lr) * 32 + lg * 8];
#pragma unroll
    for (int i = 0; i < 4; ++i) bf[i] = *(const bf16x8*)&Bs[(wn * 64 + i * 16 + lr) * 32 + lg * 8];
#pragma unroll
    for (int mi = 0; mi < 4; ++mi)
#pragma unroll
      for (int ni = 0; ni < 4; ++ni) acc[mi][ni] = MFMA(af[mi], bf[ni], acc[mi][ni]);
    __syncthreads();
  }
  float bvals[4];
#pragma unroll
  for (int ni = 0; ni < 4; ++ni) bvals[ni] = bias[n0 + wn * 64 + ni * 16 + lr];
#pragma unroll
  for (int mi = 0; mi < 4; ++mi)
#pragma unroll
    for (int ni = 0; ni < 4; ++ni)
#pragma unroll
      for (int r = 0; r < 4; ++r) {
        int m = m0 + wm * 64 + mi * 16 + lg * 4 + r;
        int n = n0 + wn * 64 + ni * 16 + lr;
        out[(size_t)m * 1024 + n] = acc[mi][ni][r] + bvals[ni];
      }
}

// ---------------------------------------------------------------------------
extern "C" void kernel_launch(void* const* d_in, const int* in_sizes, int n_in,
                              void* d_out, int out_size, void* d_ws, size_t ws_size,
                              hipStream_t stream) {
  (void)in_sizes; (void)n_in; (void)out_size; (void)ws_size;
  const float* query = (const float*)d_in[0];
  const float* key   = (const float*)d_in[1];
  const float* value = (const float*)d_in[2];
  const float* pos_k = (const float*)d_in[3];
  const float* pos_v = (const float*)d_in[4];
  const int*   mask  = (const int*)d_in[5];
  const float* rab   = (const float*)d_in[6];
  const float* Wq = (const float*)d_in[7];
  const float* bq = (const float*)d_in[8];
  const float* Wk = (const float*)d_in[9];
  const float* bk = (const float*)d_in[10];
  const float* Wv = (const float*)d_in[11];
  const float* bv = (const float*)d_in[12];
  const float* Wo = (const float*)d_in[13];
  const float* bo = (const float*)d_in[14];
  float* out = (float*)d_out;

  const size_t M2 = 2ull * 1024 * 1024;  // B*T*D elements
  short* q   = (short*)d_ws;
  short* k   = q + M2;
  short* vT  = k + M2;                    // [bh][dk][t]
  short* S   = vT + M2;                   // 32M bf16 (B,H,T,T)
  short* X0h = S + 32ull * 1024 * 1024;
  short* X   = X0h + M2;
  short* qin = X + M2;                    // stacked [3][2048][1024]
  short* kin = qin + M2;
  short* vin = kin + M2;
  short* WqT = vin + M2;                  // stacked [3+1][1024][1024]
  short* WkT = WqT + 1024 * 1024;
  short* WvT = WkT + 1024 * 1024;
  short* WoT = WvT + 1024 * 1024;

  k_cvt3<<<dim3(1024, 3), dim3(256), 0, stream>>>(query, key, value, qin, kin, vin);
  k_wtrans4<<<dim3(16, 16, 4), dim3(256), 0, stream>>>(Wq, Wk, Wv, Wo, WqT, WkT, WvT, WoT);
  k_qkv<<<dim3(8, 48), dim3(256), 0, stream>>>(qin, WqT, bq, bk, bv, q, k, vT);
  k_posk_bias<<<dim3(4, 1024), dim3(256), 0, stream>>>(q, pos_k, rab, mask, S);
  k_attn_softmax<<<dim3(32, 32), dim3(512), 0, stream>>>(q, k, S);
  k_posv<<<dim3(1024), dim3(256), 0, stream>>>(S, pos_v, X0h);
  k_av<<<dim3(8, 32), dim3(256), 0, stream>>>(S, vT, X0h, X);
  k_oproj<<<dim3(8, 16), dim3(256), 0, stream>>>(X, WoT, bo, out);
}